// Round 17
// baseline (103.284 us; speedup 1.0000x reference)
//
#include <hip/hip_runtime.h>
#include <hip/hip_bf16.h>
#include <cstdint>

#define EPS 1e-5f

typedef short bf16x8 __attribute__((ext_vector_type(8)));
typedef float f32x16 __attribute__((ext_vector_type(16)));
typedef unsigned int u32x4 __attribute__((ext_vector_type(4)));

// ws float-offsets
#define WS_TW1S 0        // 16384 ushort: chi-permuted GEMM2 A-frag layout
#define WS_FWQ  8192     // 8192 ushort: GEMM1 A-frag layout
#define WS_FBQ  12800    // 64 floats: [hi*32 + ht*16 + q]
#define WS_C2   12864    // 8 floats
#define WS_TB1V 12880    // 256 ushort: [r*8 + th] bf16 tb1s
#define WS_W2A  13056    // 2048 ushort: [((part*2+kt)*2+hi)*32+ln]*8 w2 A-frags

static __device__ __forceinline__ unsigned short f2bf(float f) {
    unsigned int u = __float_as_uint(f);
    u += 0x7fffu + ((u >> 16) & 1u);   // RNE
    return (unsigned short)(u >> 16);
}
static __device__ __forceinline__ short f2bf_fast(float f) {
    __hip_bfloat16 b = __float2bfloat16(f);
    return __builtin_bit_cast(short, b);
}
static __device__ __forceinline__ unsigned pk_bf16(float lo, float hi) {
    unsigned l = (unsigned)(unsigned short)__builtin_bit_cast(unsigned short, __float2bfloat16(lo));
    unsigned h = (unsigned)(unsigned short)__builtin_bit_cast(unsigned short, __float2bfloat16(hi));
    return l | (h << 16);
}

// chi  (GEMM1->GEMM2): j = ht*32+qq*8+4h+m -> ks = ht*2+(qq>>1), slot = 8h+(qq&1)*4+m
// chi2 (z->epilogue):  r = (e&3) + 8*((e>>2)&1) + 16*kt + 4*hi at slot 8*hi+e
// Split across 2 blocks to halve the serial tail.
__global__ void tarnet_pre(
    const float* __restrict__ fw, const float* __restrict__ fb,
    const float* __restrict__ f_gamma, const float* __restrict__ f_beta,
    const float* __restrict__ f_mean,  const float* __restrict__ f_var,
    const float* __restrict__ tw1, const float* __restrict__ tb1,
    const float* __restrict__ t_gamma, const float* __restrict__ t_beta,
    const float* __restrict__ t_mean,  const float* __restrict__ t_var,
    const float* __restrict__ tw2, const float* __restrict__ tb2,
    float* __restrict__ ws)
{
    __shared__ float fs[64], fsh[64];
    const int i = threadIdx.x;  // 256 threads
    if (i < 64) {
        float s = f_gamma[i] * rsqrtf(f_var[i] + EPS);
        fs[i]  = s;
        fsh[i] = f_beta[i] - f_mean[i] * s;
    }
    __syncthreads();

    unsigned short* tw1s_u = (unsigned short*)(ws + WS_TW1S);
    unsigned short* fwq_u  = (unsigned short*)(ws + WS_FWQ);
    unsigned short* tb1v_u = (unsigned short*)(ws + WS_TB1V);
    unsigned short* w2a_u  = (unsigned short*)(ws + WS_W2A);

    if (blockIdx.x == 0) {
        const int t = i >> 5, r = i & 31;
        const int idx = t * 32 + r;
        float tsc  = t_gamma[idx] * rsqrtf(t_var[idx] + EPS);
        float tb1s = tb1[idx];
        for (int j = 0; j < 64; ++j) {
            float w = tw1[idx * 64 + j];
            tb1s += w * fsh[j];
            int ht = j >> 5, qq = (j >> 3) & 3, h = (j >> 2) & 1, m = j & 3;
            int ks = ht * 2 + (qq >> 1);
            int ep = (qq & 1) * 4 + m;
            tw1s_u[(((t*4 + ks)*2 + h)*32 + r)*8 + ep] = f2bf(w * fs[j]);
        }
        tb1v_u[r*8 + t] = f2bf(tb1s);
        if (r == 0) {
            float a = tb2[t];
            for (int rr = 0; rr < 32; ++rr) {
                int id2 = t*32 + rr;
                float ts2 = t_gamma[id2] * rsqrtf(t_var[id2] + EPS);
                a += tw2[id2] * (t_beta[id2] - ts2 * t_mean[id2]);
            }
            ws[WS_C2 + t] = a;
        }
    } else {
        {   // fw conversion, frag-native
            const int hc = i >> 2, kq = (i & 3) * 32;
            for (int kk = 0; kk < 32; ++kk) {
                const int k = kq + kk;
                const int ks = k >> 4, h = (k >> 3) & 1, jj = k & 7;
                fwq_u[(((ks*2 + h)*64) + hc)*8 + jj] = f2bf(fw[hc*128 + k]);
            }
        }
        if (i < 64) {
            int ht = i >> 5, r32 = i & 31;
            int q  = ((r32 >> 3) << 2) | (r32 & 3);
            int hq = (r32 >> 2) & 1;
            ws[WS_FBQ + hq*32 + ht*16 + q] = fb[i];
        }
        {   // W2A: epilogue A-frags (R12-validated)
            const int ln = i & 31, hh = (i >> 5) & 1, kt = (i >> 6) & 1, part = i >> 7;
            const int base = (((part*2 + kt)*2 + hh)*32 + ln)*8;
            for (int e = 0; e < 8; ++e) {
                unsigned short v = 0;
                if (ln < 8) {
                    const int rr = (e & 3) + 8*((e >> 2) & 1) + 16*kt + 4*hh;
                    const int id2 = ln*32 + rr;
                    float tsc = t_gamma[id2] * rsqrtf(t_var[id2] + EPS);
                    float w = tw2[id2] * tsc;
                    if (part == 0) v = f2bf(w);
                    else {
                        float whi = __uint_as_float(((unsigned)f2bf(w)) << 16);
                        v = f2bf(w - whi);
                    }
                }
                w2a_u[base + e] = v;
            }
        }
    }
}

#define NT 4   // 128-sample tiles per block

// 4 waves/block, dbuf bf16 x-tiles (2x32 KB), issue-early staging, MFMA epilogue.
__global__ __launch_bounds__(256, 2) void tarnet_main(
    const float* __restrict__ x, const int* __restrict__ t_arr,
    const float* __restrict__ ws, float* __restrict__ out)
{
    __shared__ unsigned short xls[2][128 * 128];   // 2 x 32 KB, XOR-swizzled

    const int tid  = threadIdx.x;
    const int wave = tid >> 6, lane = tid & 63;
    const int ln31 = lane & 31, hi = lane >> 5;
    const int tile0 = blockIdx.x * NT;

    const unsigned short* fwq_u  = (const unsigned short*)(ws + WS_FWQ);
    const unsigned short* tw1s_u = (const unsigned short*)(ws + WS_TW1S);
    const unsigned short* w2a_u  = (const unsigned short*)(ws + WS_W2A);

    // ---- hoisted wave-invariant tables ----
    bf16x8 w2f[4];
#pragma unroll
    for (int pk = 0; pk < 4; ++pk)
        w2f[pk] = *(const bf16x8*)(w2a_u + ((pk*2 + hi)*32 + ln31)*8);
    const bf16x8 tb1v = *(const bf16x8*)((const unsigned short*)(ws + WS_TB1V) + ln31*8);
    u32x4 hbv = { hi ? 0u : 0x3F80u, 0u, 0u, 0u };   // const-1 B-frag, slot0
    const bf16x8 hbias = __builtin_bit_cast(bf16x8, hbv);
    float fbi[32];
    {
        const float4* f4 = (const float4*)(ws + WS_FBQ);
#pragma unroll
        for (int i2 = 0; i2 < 8; ++i2) {
            float4 v = f4[hi*8 + i2];
            fbi[4*i2+0] = v.x; fbi[4*i2+1] = v.y;
            fbi[4*i2+2] = v.z; fbi[4*i2+3] = v.w;
        }
    }

    // staging helpers: pair index i = it*256+tid -> row=i>>4, pcol=i&15
    float4 pf[16];
    auto LOAD = [&](int T) {
        const float4* xg = (const float4*)(x + (size_t)T * 128 * 128);
#pragma unroll
        for (int it = 0; it < 8; ++it) {
            const int i = it * 256 + tid;
            pf[2*it]   = xg[2*i];
            pf[2*it+1] = xg[2*i + 1];
        }
    };
    auto WRITE = [&](int b) {
        char* xl = (char*)xls[b];
#pragma unroll
        for (int it = 0; it < 8; ++it) {
            const int i = it * 256 + tid;
            float4 a = pf[2*it], c = pf[2*it+1];
            bf16x8 v;
            v[0] = f2bf_fast(a.x); v[1] = f2bf_fast(a.y);
            v[2] = f2bf_fast(a.z); v[3] = f2bf_fast(a.w);
            v[4] = f2bf_fast(c.x); v[5] = f2bf_fast(c.y);
            v[6] = f2bf_fast(c.z); v[7] = f2bf_fast(c.w);
            const int row = i >> 4, pcol = i & 15;
            *(bf16x8*)(xl + row * 256 + ((pcol * 16) ^ ((row & 15) << 4))) = v;
        }
    };

    // prologue: tile0 -> buf0
    LOAD(tile0);
    WRITE(0);
    __syncthreads();

    const int srow = wave * 32 + ln31;
    const int rb = srow * 256, swz = (srow & 15) << 4;

#pragma unroll 1
    for (int it = 0; it < NT; ++it) {
        const int T = tile0 + it;
        const int s0 = T * 128;
        const int cur = it & 1;

        // ---- issue next tile's loads: in flight across compute ----
        if (it + 1 < NT) LOAD(T + 1);
        __builtin_amdgcn_sched_barrier(0);

        const char* xl = (const char*)xls[cur];
        const int tsel = t_arr[s0 + wave * 32 + ln31];

        // ---- GEMM1: h^T = fw @ x^T (+fb) ----
        f32x16 acc[2];
#pragma unroll
        for (int ht = 0; ht < 2; ++ht)
#pragma unroll
            for (int q = 0; q < 16; ++q) acc[ht][q] = fbi[ht*16 + q];
#pragma unroll
        for (int ks = 0; ks < 8; ++ks) {
            bf16x8 wa0 = *(const bf16x8*)(fwq_u + (((ks*2 + hi)*64) + ln31     )*8);
            bf16x8 wa1 = *(const bf16x8*)(fwq_u + (((ks*2 + hi)*64) + ln31 + 32)*8);
            bf16x8 xf  = *(const bf16x8*)(xl + rb + ((ks*32 + hi*16) ^ swz));
            acc[0] = __builtin_amdgcn_mfma_f32_32x32x16_bf16(wa0, xf, acc[0], 0, 0, 0);
            acc[1] = __builtin_amdgcn_mfma_f32_32x32x16_bf16(wa1, xf, acc[1], 0, 0, 0);
        }

        // ---- relu -> chi-pack: lane-local B-frags ----
        bf16x8 hb[4];
        {
            unsigned w0[2][4], w1[2][4];
#pragma unroll
            for (int ht = 0; ht < 2; ++ht)
#pragma unroll
                for (int qq = 0; qq < 4; ++qq) {
                    float a0 = fmaxf(acc[ht][qq*4+0], 0.f);
                    float a1 = fmaxf(acc[ht][qq*4+1], 0.f);
                    float a2 = fmaxf(acc[ht][qq*4+2], 0.f);
                    float a3 = fmaxf(acc[ht][qq*4+3], 0.f);
                    w0[ht][qq] = pk_bf16(a0, a1);
                    w1[ht][qq] = pk_bf16(a2, a3);
                }
#pragma unroll
            for (int ks = 0; ks < 4; ++ks) {
                const int ht = ks >> 1, qa = (ks & 1) * 2;
                u32x4 wv = {w0[ht][qa], w1[ht][qa], w0[ht][qa+1], w1[ht][qa+1]};
                hb[ks] = __builtin_bit_cast(bf16x8, wv);
            }
        }

        // ---- GEMM2 dense 8 heads, MFMA bias + MFMA epilogue (R12/R13-validated) ----
        float outv = 0.f;
#pragma unroll
        for (int th = 0; th < 8; ++th) {
            bf16x8 aw0 = *(const bf16x8*)(tw1s_u + (((th*4 + 0)*2 + hi)*32 + ln31)*8);
            bf16x8 aw1 = *(const bf16x8*)(tw1s_u + (((th*4 + 1)*2 + hi)*32 + ln31)*8);
            bf16x8 aw2 = *(const bf16x8*)(tw1s_u + (((th*4 + 2)*2 + hi)*32 + ln31)*8);
            bf16x8 aw3 = *(const bf16x8*)(tw1s_u + (((th*4 + 3)*2 + hi)*32 + ln31)*8);
            f32x16 z = {0.f};
            z = __builtin_amdgcn_mfma_f32_32x32x16_bf16(aw0, hb[0], z, 0, 0, 0);
            z = __builtin_amdgcn_mfma_f32_32x32x16_bf16(aw1, hb[1], z, 0, 0, 0);
            z = __builtin_amdgcn_mfma_f32_32x32x16_bf16(aw2, hb[2], z, 0, 0, 0);
            z = __builtin_amdgcn_mfma_f32_32x32x16_bf16(aw3, hb[3], z, 0, 0, 0);
            u32x4 tbv = { hi ? 0u : (unsigned)(unsigned short)tb1v[th], 0u, 0u, 0u };
            z = __builtin_amdgcn_mfma_f32_32x32x16_bf16(
                    __builtin_bit_cast(bf16x8, tbv), hbias, z, 0, 0, 0);

            bf16x8 zb[2];
#pragma unroll
            for (int kt = 0; kt < 2; ++kt) {
                u32x4 wv;
#pragma unroll
                for (int wd = 0; wd < 4; ++wd)
                    wv[wd] = pk_bf16(fmaxf(z[8*kt + 2*wd], 0.f),
                                     fmaxf(z[8*kt + 2*wd + 1], 0.f));
                zb[kt] = __builtin_bit_cast(bf16x8, wv);
            }
            f32x16 d = {0.f};
            d = __builtin_amdgcn_mfma_f32_32x32x16_bf16(w2f[0], zb[0], d, 0, 0, 0);
            d = __builtin_amdgcn_mfma_f32_32x32x16_bf16(w2f[1], zb[1], d, 0, 0, 0);
            d = __builtin_amdgcn_mfma_f32_32x32x16_bf16(w2f[2], zb[0], d, 0, 0, 0);
            d = __builtin_amdgcn_mfma_f32_32x32x16_bf16(w2f[3], zb[1], d, 0, 0, 0);

            float cand  = d[th & 3];
            float other = __shfl_xor(cand, 32);
            float val   = (hi == (th >> 2)) ? cand : other;
            outv = (th == tsel) ? val : outv;
        }
        outv += ws[WS_C2 + tsel];
        if (!hi) out[s0 + wave * 32 + ln31] = outv;

        // ---- land next tile: wait loads, write other buffer ----
        if (it + 1 < NT) {
            asm volatile("s_waitcnt vmcnt(0)" ::: "memory");
            __syncthreads();          // everyone done reading buf cur^1 (prev tile)
            WRITE(cur ^ 1);
            __syncthreads();          // writes visible before next compute
        }
    }
}

extern "C" void kernel_launch(void* const* d_in, const int* in_sizes, int n_in,
                              void* d_out, int out_size, void* d_ws, size_t ws_size,
                              hipStream_t stream) {
    const float* x       = (const float*)d_in[0];
    const int*   t       = (const int*)  d_in[1];
    const float* fw      = (const float*)d_in[2];
    const float* fb      = (const float*)d_in[3];
    const float* f_gamma = (const float*)d_in[4];
    const float* f_beta  = (const float*)d_in[5];
    const float* f_mean  = (const float*)d_in[6];
    const float* f_var   = (const float*)d_in[7];
    const float* tw1     = (const float*)d_in[8];
    const float* tb1     = (const float*)d_in[9];
    const float* t_gamma = (const float*)d_in[10];
    const float* t_beta  = (const float*)d_in[11];
    const float* t_mean  = (const float*)d_in[12];
    const float* t_var   = (const float*)d_in[13];
    const float* tw2     = (const float*)d_in[14];
    const float* tb2     = (const float*)d_in[15];

    float* ws   = (float*)d_ws;
    float* outp = (float*)d_out;
    const int B = in_sizes[0] / 128;   // 262144

    tarnet_pre<<<2, 256, 0, stream>>>(fw, fb, f_gamma, f_beta, f_mean, f_var,
                                      tw1, tb1, t_gamma, t_beta, t_mean, t_var,
                                      tw2, tb2, ws);
    tarnet_main<<<B / (128 * NT), 256, 0, stream>>>(x, t, ws, outp);
}

// Round 18
// 103.205 us; speedup vs baseline: 1.0008x; 1.0008x over previous
//
#include <hip/hip_runtime.h>
#include <hip/hip_bf16.h>
#include <cstdint>

#define EPS 1e-5f

typedef short bf16x8 __attribute__((ext_vector_type(8)));
typedef float f32x16 __attribute__((ext_vector_type(16)));
typedef unsigned int u32x4 __attribute__((ext_vector_type(4)));

// ws float-offsets
#define WS_TW1S 0        // 16384 ushort: chi-permuted GEMM2 A-frag layout
#define WS_FWQ  8192     // 8192 ushort: GEMM1 A-frag layout
#define WS_FBQ  12800    // 64 floats: [hi*32 + ht*16 + q]
#define WS_C2   12864    // 8 floats
#define WS_TB1V 12880    // 256 ushort: [r*8 + th] bf16 tb1s
#define WS_W2A  13056    // 2048 ushort: [((part*2+kt)*2+hi)*32+ln]*8 w2 A-frags

static __device__ __forceinline__ unsigned short f2bf(float f) {
    unsigned int u = __float_as_uint(f);
    u += 0x7fffu + ((u >> 16) & 1u);   // RNE
    return (unsigned short)(u >> 16);
}
static __device__ __forceinline__ short f2bf_fast(float f) {
    __hip_bfloat16 b = __float2bfloat16(f);
    return __builtin_bit_cast(short, b);
}
static __device__ __forceinline__ unsigned pk_bf16(float lo, float hi) {
    unsigned l = (unsigned)(unsigned short)__builtin_bit_cast(unsigned short, __float2bfloat16(lo));
    unsigned h = (unsigned)(unsigned short)__builtin_bit_cast(unsigned short, __float2bfloat16(hi));
    return l | (h << 16);
}

// chi  (GEMM1->GEMM2): j = ht*32+qq*8+4h+m -> ks = ht*2+(qq>>1), slot = 8h+(qq&1)*4+m
// chi2 (z->epilogue):  r = (e&3) + 8*((e>>2)&1) + 16*kt + 4*hi at slot 8*hi+e
// Split across 2 blocks to halve the serial tail.
__global__ void tarnet_pre(
    const float* __restrict__ fw, const float* __restrict__ fb,
    const float* __restrict__ f_gamma, const float* __restrict__ f_beta,
    const float* __restrict__ f_mean,  const float* __restrict__ f_var,
    const float* __restrict__ tw1, const float* __restrict__ tb1,
    const float* __restrict__ t_gamma, const float* __restrict__ t_beta,
    const float* __restrict__ t_mean,  const float* __restrict__ t_var,
    const float* __restrict__ tw2, const float* __restrict__ tb2,
    float* __restrict__ ws)
{
    __shared__ float fs[64], fsh[64];
    const int i = threadIdx.x;  // 256 threads
    if (i < 64) {
        float s = f_gamma[i] * rsqrtf(f_var[i] + EPS);
        fs[i]  = s;
        fsh[i] = f_beta[i] - f_mean[i] * s;
    }
    __syncthreads();

    unsigned short* tw1s_u = (unsigned short*)(ws + WS_TW1S);
    unsigned short* fwq_u  = (unsigned short*)(ws + WS_FWQ);
    unsigned short* tb1v_u = (unsigned short*)(ws + WS_TB1V);
    unsigned short* w2a_u  = (unsigned short*)(ws + WS_W2A);

    if (blockIdx.x == 0) {
        const int t = i >> 5, r = i & 31;
        const int idx = t * 32 + r;
        float tsc  = t_gamma[idx] * rsqrtf(t_var[idx] + EPS);
        float tb1s = tb1[idx];
        for (int j = 0; j < 64; ++j) {
            float w = tw1[idx * 64 + j];
            tb1s += w * fsh[j];
            int ht = j >> 5, qq = (j >> 3) & 3, h = (j >> 2) & 1, m = j & 3;
            int ks = ht * 2 + (qq >> 1);
            int ep = (qq & 1) * 4 + m;
            tw1s_u[(((t*4 + ks)*2 + h)*32 + r)*8 + ep] = f2bf(w * fs[j]);
        }
        tb1v_u[r*8 + t] = f2bf(tb1s);
        if (r == 0) {
            float a = tb2[t];
            for (int rr = 0; rr < 32; ++rr) {
                int id2 = t*32 + rr;
                float ts2 = t_gamma[id2] * rsqrtf(t_var[id2] + EPS);
                a += tw2[id2] * (t_beta[id2] - ts2 * t_mean[id2]);
            }
            ws[WS_C2 + t] = a;
        }
    } else {
        {   // fw conversion, frag-native
            const int hc = i >> 2, kq = (i & 3) * 32;
            for (int kk = 0; kk < 32; ++kk) {
                const int k = kq + kk;
                const int ks = k >> 4, h = (k >> 3) & 1, jj = k & 7;
                fwq_u[(((ks*2 + h)*64) + hc)*8 + jj] = f2bf(fw[hc*128 + k]);
            }
        }
        if (i < 64) {
            int ht = i >> 5, r32 = i & 31;
            int q  = ((r32 >> 3) << 2) | (r32 & 3);
            int hq = (r32 >> 2) & 1;
            ws[WS_FBQ + hq*32 + ht*16 + q] = fb[i];
        }
        {   // W2A: epilogue A-frags (R12-validated)
            const int ln = i & 31, hh = (i >> 5) & 1, kt = (i >> 6) & 1, part = i >> 7;
            const int base = (((part*2 + kt)*2 + hh)*32 + ln)*8;
            for (int e = 0; e < 8; ++e) {
                unsigned short v = 0;
                if (ln < 8) {
                    const int rr = (e & 3) + 8*((e >> 2) & 1) + 16*kt + 4*hh;
                    const int id2 = ln*32 + rr;
                    float tsc = t_gamma[id2] * rsqrtf(t_var[id2] + EPS);
                    float w = tw2[id2] * tsc;
                    if (part == 0) v = f2bf(w);
                    else {
                        float whi = __uint_as_float(((unsigned)f2bf(w)) << 16);
                        v = f2bf(w - whi);
                    }
                }
                w2a_u[base + e] = v;
            }
        }
    }
}

#define NT 4   // 128-sample tiles per block

// 4 waves/block, dbuf bf16 x-tiles (2x32 KB), issue-early staging, MFMA epilogue.
__global__ __launch_bounds__(256, 2) void tarnet_main(
    const float* __restrict__ x, const int* __restrict__ t_arr,
    const float* __restrict__ ws, float* __restrict__ out)
{
    __shared__ unsigned short xls[2][128 * 128];   // 2 x 32 KB, XOR-swizzled

    const int tid  = threadIdx.x;
    const int wave = tid >> 6, lane = tid & 63;
    const int ln31 = lane & 31, hi = lane >> 5;
    const int tile0 = blockIdx.x * NT;

    const unsigned short* fwq_u  = (const unsigned short*)(ws + WS_FWQ);
    const unsigned short* tw1s_u = (const unsigned short*)(ws + WS_TW1S);
    const unsigned short* w2a_u  = (const unsigned short*)(ws + WS_W2A);

    // ---- hoisted wave-invariant tables ----
    bf16x8 w2f[4];
#pragma unroll
    for (int pk = 0; pk < 4; ++pk)
        w2f[pk] = *(const bf16x8*)(w2a_u + ((pk*2 + hi)*32 + ln31)*8);
    const bf16x8 tb1v = *(const bf16x8*)((const unsigned short*)(ws + WS_TB1V) + ln31*8);
    u32x4 hbv = { hi ? 0u : 0x3F80u, 0u, 0u, 0u };   // const-1 B-frag, slot0
    const bf16x8 hbias = __builtin_bit_cast(bf16x8, hbv);
    float fbi[32];
    {
        const float4* f4 = (const float4*)(ws + WS_FBQ);
#pragma unroll
        for (int i2 = 0; i2 < 8; ++i2) {
            float4 v = f4[hi*8 + i2];
            fbi[4*i2+0] = v.x; fbi[4*i2+1] = v.y;
            fbi[4*i2+2] = v.z; fbi[4*i2+3] = v.w;
        }
    }

    // staging helpers: pair index i = it*256+tid -> row=i>>4, pcol=i&15
    float4 pf[16];
    auto LOAD = [&](int T) {
        const float4* xg = (const float4*)(x + (size_t)T * 128 * 128);
#pragma unroll
        for (int it = 0; it < 8; ++it) {
            const int i = it * 256 + tid;
            pf[2*it]   = xg[2*i];
            pf[2*it+1] = xg[2*i + 1];
        }
    };
    auto WRITE = [&](int b) {
        char* xl = (char*)xls[b];
#pragma unroll
        for (int it = 0; it < 8; ++it) {
            const int i = it * 256 + tid;
            float4 a = pf[2*it], c = pf[2*it+1];
            bf16x8 v;
            v[0] = f2bf_fast(a.x); v[1] = f2bf_fast(a.y);
            v[2] = f2bf_fast(a.z); v[3] = f2bf_fast(a.w);
            v[4] = f2bf_fast(c.x); v[5] = f2bf_fast(c.y);
            v[6] = f2bf_fast(c.z); v[7] = f2bf_fast(c.w);
            const int row = i >> 4, pcol = i & 15;
            *(bf16x8*)(xl + row * 256 + ((pcol * 16) ^ ((row & 15) << 4))) = v;
        }
    };

    // prologue: tile0 -> buf0
    LOAD(tile0);
    WRITE(0);
    __syncthreads();

    const int srow = wave * 32 + ln31;
    const int rb = srow * 256, swz = (srow & 15) << 4;

#pragma unroll 1
    for (int it = 0; it < NT; ++it) {
        const int T = tile0 + it;
        const int s0 = T * 128;
        const int cur = it & 1;

        // ---- issue next tile's loads: in flight across compute ----
        if (it + 1 < NT) LOAD(T + 1);
        __builtin_amdgcn_sched_barrier(0);

        const char* xl = (const char*)xls[cur];
        const int tsel = t_arr[s0 + wave * 32 + ln31];

        // ---- GEMM1: h^T = fw @ x^T (+fb) ----
        f32x16 acc[2];
#pragma unroll
        for (int ht = 0; ht < 2; ++ht)
#pragma unroll
            for (int q = 0; q < 16; ++q) acc[ht][q] = fbi[ht*16 + q];
#pragma unroll
        for (int ks = 0; ks < 8; ++ks) {
            bf16x8 wa0 = *(const bf16x8*)(fwq_u + (((ks*2 + hi)*64) + ln31     )*8);
            bf16x8 wa1 = *(const bf16x8*)(fwq_u + (((ks*2 + hi)*64) + ln31 + 32)*8);
            bf16x8 xf  = *(const bf16x8*)(xl + rb + ((ks*32 + hi*16) ^ swz));
            acc[0] = __builtin_amdgcn_mfma_f32_32x32x16_bf16(wa0, xf, acc[0], 0, 0, 0);
            acc[1] = __builtin_amdgcn_mfma_f32_32x32x16_bf16(wa1, xf, acc[1], 0, 0, 0);
        }

        // ---- relu -> chi-pack: lane-local B-frags ----
        bf16x8 hb[4];
        {
            unsigned w0[2][4], w1[2][4];
#pragma unroll
            for (int ht = 0; ht < 2; ++ht)
#pragma unroll
                for (int qq = 0; qq < 4; ++qq) {
                    float a0 = fmaxf(acc[ht][qq*4+0], 0.f);
                    float a1 = fmaxf(acc[ht][qq*4+1], 0.f);
                    float a2 = fmaxf(acc[ht][qq*4+2], 0.f);
                    float a3 = fmaxf(acc[ht][qq*4+3], 0.f);
                    w0[ht][qq] = pk_bf16(a0, a1);
                    w1[ht][qq] = pk_bf16(a2, a3);
                }
#pragma unroll
            for (int ks = 0; ks < 4; ++ks) {
                const int ht = ks >> 1, qa = (ks & 1) * 2;
                u32x4 wv = {w0[ht][qa], w1[ht][qa], w0[ht][qa+1], w1[ht][qa+1]};
                hb[ks] = __builtin_bit_cast(bf16x8, wv);
            }
        }

        // ---- GEMM2 dense 8 heads, MFMA bias + MFMA epilogue (R12/R13-validated) ----
        float outv = 0.f;
#pragma unroll
        for (int th = 0; th < 8; ++th) {
            bf16x8 aw0 = *(const bf16x8*)(tw1s_u + (((th*4 + 0)*2 + hi)*32 + ln31)*8);
            bf16x8 aw1 = *(const bf16x8*)(tw1s_u + (((th*4 + 1)*2 + hi)*32 + ln31)*8);
            bf16x8 aw2 = *(const bf16x8*)(tw1s_u + (((th*4 + 2)*2 + hi)*32 + ln31)*8);
            bf16x8 aw3 = *(const bf16x8*)(tw1s_u + (((th*4 + 3)*2 + hi)*32 + ln31)*8);
            f32x16 z = {0.f};
            z = __builtin_amdgcn_mfma_f32_32x32x16_bf16(aw0, hb[0], z, 0, 0, 0);
            z = __builtin_amdgcn_mfma_f32_32x32x16_bf16(aw1, hb[1], z, 0, 0, 0);
            z = __builtin_amdgcn_mfma_f32_32x32x16_bf16(aw2, hb[2], z, 0, 0, 0);
            z = __builtin_amdgcn_mfma_f32_32x32x16_bf16(aw3, hb[3], z, 0, 0, 0);
            u32x4 tbv = { hi ? 0u : (unsigned)(unsigned short)tb1v[th], 0u, 0u, 0u };
            z = __builtin_amdgcn_mfma_f32_32x32x16_bf16(
                    __builtin_bit_cast(bf16x8, tbv), hbias, z, 0, 0, 0);

            bf16x8 zb[2];
#pragma unroll
            for (int kt = 0; kt < 2; ++kt) {
                u32x4 wv;
#pragma unroll
                for (int wd = 0; wd < 4; ++wd)
                    wv[wd] = pk_bf16(fmaxf(z[8*kt + 2*wd], 0.f),
                                     fmaxf(z[8*kt + 2*wd + 1], 0.f));
                zb[kt] = __builtin_bit_cast(bf16x8, wv);
            }
            f32x16 d = {0.f};
            d = __builtin_amdgcn_mfma_f32_32x32x16_bf16(w2f[0], zb[0], d, 0, 0, 0);
            d = __builtin_amdgcn_mfma_f32_32x32x16_bf16(w2f[1], zb[1], d, 0, 0, 0);
            d = __builtin_amdgcn_mfma_f32_32x32x16_bf16(w2f[2], zb[0], d, 0, 0, 0);
            d = __builtin_amdgcn_mfma_f32_32x32x16_bf16(w2f[3], zb[1], d, 0, 0, 0);

            float cand  = d[th & 3];
            float other = __shfl_xor(cand, 32);
            float val   = (hi == (th >> 2)) ? cand : other;
            outv = (th == tsel) ? val : outv;
        }
        outv += ws[WS_C2 + tsel];
        if (!hi) out[s0 + wave * 32 + ln31] = outv;

        // ---- land next tile: wait loads, write other buffer ----
        if (it + 1 < NT) {
            asm volatile("s_waitcnt vmcnt(0)" ::: "memory");
            __syncthreads();          // everyone done reading buf cur^1 (prev tile)
            WRITE(cur ^ 1);
            __syncthreads();          // writes visible before next compute
        }
    }
}

extern "C" void kernel_launch(void* const* d_in, const int* in_sizes, int n_in,
                              void* d_out, int out_size, void* d_ws, size_t ws_size,
                              hipStream_t stream) {
    const float* x       = (const float*)d_in[0];
    const int*   t       = (const int*)  d_in[1];
    const float* fw      = (const float*)d_in[2];
    const float* fb      = (const float*)d_in[3];
    const float* f_gamma = (const float*)d_in[4];
    const float* f_beta  = (const float*)d_in[5];
    const float* f_mean  = (const float*)d_in[6];
    const float* f_var   = (const float*)d_in[7];
    const float* tw1     = (const float*)d_in[8];
    const float* tb1     = (const float*)d_in[9];
    const float* t_gamma = (const float*)d_in[10];
    const float* t_beta  = (const float*)d_in[11];
    const float* t_mean  = (const float*)d_in[12];
    const float* t_var   = (const float*)d_in[13];
    const float* tw2     = (const float*)d_in[14];
    const float* tb2     = (const float*)d_in[15];

    float* ws   = (float*)d_ws;
    float* outp = (float*)d_out;
    const int B = in_sizes[0] / 128;   // 262144

    tarnet_pre<<<2, 256, 0, stream>>>(fw, fb, f_gamma, f_beta, f_mean, f_var,
                                      tw1, tb1, t_gamma, t_beta, t_mean, t_var,
                                      tw2, tb2, ws);
    tarnet_main<<<B / (128 * NT), 256, 0, stream>>>(x, t, ws, outp);
}

// Round 19
// 65.288 us; speedup vs baseline: 1.5820x; 1.5808x over previous
//
#include <hip/hip_runtime.h>
#include <hip/hip_bf16.h>
#include <cstdint>

#define EPS 1e-5f

typedef short bf16x8 __attribute__((ext_vector_type(8)));
typedef float f32x16 __attribute__((ext_vector_type(16)));
typedef unsigned int u32x4 __attribute__((ext_vector_type(4)));

// ws float-offsets
#define WS_TW1S 0        // 16384 ushort: chi-permuted GEMM2 A-frag layout
#define WS_FWQ  8192     // 8192 ushort: GEMM1 A-frag layout
#define WS_FBQ  12800    // 64 floats: [hi*32 + ht*16 + q]
#define WS_C2   12864    // 8 floats
#define WS_TB1V 12880    // 256 ushort: [r*8 + th] bf16 tb1s
#define WS_W2A  13056    // 2048 ushort: [((part*2+kt)*2+hi)*32+ln]*8 w2 A-frags

static __device__ __forceinline__ unsigned short f2bf(float f) {
    unsigned int u = __float_as_uint(f);
    u += 0x7fffu + ((u >> 16) & 1u);   // RNE
    return (unsigned short)(u >> 16);
}
static __device__ __forceinline__ short f2bf_fast(float f) {
    __hip_bfloat16 b = __float2bfloat16(f);
    return __builtin_bit_cast(short, b);
}
static __device__ __forceinline__ unsigned pk_bf16(float lo, float hi) {
    unsigned l = (unsigned)(unsigned short)__builtin_bit_cast(unsigned short, __float2bfloat16(lo));
    unsigned h = (unsigned)(unsigned short)__builtin_bit_cast(unsigned short, __float2bfloat16(hi));
    return l | (h << 16);
}

// chi  (GEMM1->GEMM2): j = ht*32+qq*8+4h+m -> ks = ht*2+(qq>>1), slot = 8h+(qq&1)*4+m
// chi2 (z->epilogue):  r = (e&3) + 8*((e>>2)&1) + 16*kt + 4*hi at slot 8*hi+e
__global__ void tarnet_pre(
    const float* __restrict__ fw, const float* __restrict__ fb,
    const float* __restrict__ f_gamma, const float* __restrict__ f_beta,
    const float* __restrict__ f_mean,  const float* __restrict__ f_var,
    const float* __restrict__ tw1, const float* __restrict__ tb1,
    const float* __restrict__ t_gamma, const float* __restrict__ t_beta,
    const float* __restrict__ t_mean,  const float* __restrict__ t_var,
    const float* __restrict__ tw2, const float* __restrict__ tb2,
    float* __restrict__ ws)
{
    __shared__ float fs[64], fsh[64];
    const int i = threadIdx.x;  // 256 threads
    if (i < 64) {
        float s = f_gamma[i] * rsqrtf(f_var[i] + EPS);
        fs[i]  = s;
        fsh[i] = f_beta[i] - f_mean[i] * s;
    }
    __syncthreads();

    unsigned short* tw1s_u = (unsigned short*)(ws + WS_TW1S);
    unsigned short* fwq_u  = (unsigned short*)(ws + WS_FWQ);
    unsigned short* tb1v_u = (unsigned short*)(ws + WS_TB1V);
    unsigned short* w2a_u  = (unsigned short*)(ws + WS_W2A);

    if (blockIdx.x == 0) {
        const int t = i >> 5, r = i & 31;
        const int idx = t * 32 + r;
        float tsc  = t_gamma[idx] * rsqrtf(t_var[idx] + EPS);
        float tb1s = tb1[idx];
        for (int j = 0; j < 64; ++j) {
            float w = tw1[idx * 64 + j];
            tb1s += w * fsh[j];
            int ht = j >> 5, qq = (j >> 3) & 3, h = (j >> 2) & 1, m = j & 3;
            int ks = ht * 2 + (qq >> 1);
            int ep = (qq & 1) * 4 + m;
            tw1s_u[(((t*4 + ks)*2 + h)*32 + r)*8 + ep] = f2bf(w * fs[j]);
        }
        tb1v_u[r*8 + t] = f2bf(tb1s);
        if (r == 0) {
            float a = tb2[t];
            for (int rr = 0; rr < 32; ++rr) {
                int id2 = t*32 + rr;
                float ts2 = t_gamma[id2] * rsqrtf(t_var[id2] + EPS);
                a += tw2[id2] * (t_beta[id2] - ts2 * t_mean[id2]);
            }
            ws[WS_C2 + t] = a;
        }
    } else {
        {   // fw conversion, frag-native
            const int hc = i >> 2, kq = (i & 3) * 32;
            for (int kk = 0; kk < 32; ++kk) {
                const int k = kq + kk;
                const int ks = k >> 4, h = (k >> 3) & 1, jj = k & 7;
                fwq_u[(((ks*2 + h)*64) + hc)*8 + jj] = f2bf(fw[hc*128 + k]);
            }
        }
        if (i < 64) {
            int ht = i >> 5, r32 = i & 31;
            int q  = ((r32 >> 3) << 2) | (r32 & 3);
            int hq = (r32 >> 2) & 1;
            ws[WS_FBQ + hq*32 + ht*16 + q] = fb[i];
        }
        {   // W2A: epilogue A-frags (R12-validated)
            const int ln = i & 31, hh = (i >> 5) & 1, kt = (i >> 6) & 1, part = i >> 7;
            const int base = (((part*2 + kt)*2 + hh)*32 + ln)*8;
            for (int e = 0; e < 8; ++e) {
                unsigned short v = 0;
                if (ln < 8) {
                    const int rr = (e & 3) + 8*((e >> 2) & 1) + 16*kt + 4*hh;
                    const int id2 = ln*32 + rr;
                    float tsc = t_gamma[id2] * rsqrtf(t_var[id2] + EPS);
                    float w = tw2[id2] * tsc;
                    if (part == 0) v = f2bf(w);
                    else {
                        float whi = __uint_as_float(((unsigned)f2bf(w)) << 16);
                        v = f2bf(w - whi);
                    }
                }
                w2a_u[base + e] = v;
            }
        }
    }
}

#define NTW 8   // 32-sample tiles per wave

// 1 block/CU (128 KB LDS), 4 waves; wave-private f32 dbuf fed by global_load_lds,
// counted vmcnt pipeline; ALL tables register-resident; zero barriers.
__global__ __launch_bounds__(256, 1) void tarnet_main(
    const float* __restrict__ x, const int* __restrict__ t_arr,
    const float* __restrict__ ws, float* __restrict__ out)
{
    __shared__ uint4 xls[8192];   // 128 KB: [wave][buf][1024 uint4 = 16 KB]

    const int tid  = threadIdx.x;
    const int wave = tid >> 6, lane = tid & 63;
    const int ln31 = lane & 31, hi = lane >> 5;
    const int wid = blockIdx.x * 4 + wave;
    const int t0 = wid * NTW;

    const unsigned short* fwq_u  = (const unsigned short*)(ws + WS_FWQ);
    const unsigned short* tw1s_u = (const unsigned short*)(ws + WS_TW1S);
    const unsigned short* w2a_u  = (const unsigned short*)(ws + WS_W2A);

    // ---- hoist ALL tables to registers (no global reads in steady loop) ----
    bf16x8 wa[8][2];   // GEMM1 A-frags, 64 VGPR
#pragma unroll
    for (int ks = 0; ks < 8; ++ks) {
        wa[ks][0] = *(const bf16x8*)(fwq_u + (((ks*2 + hi)*64) + ln31     )*8);
        wa[ks][1] = *(const bf16x8*)(fwq_u + (((ks*2 + hi)*64) + ln31 + 32)*8);
    }
    bf16x8 aw[8][4];   // GEMM2 A-frags, 128 VGPR
#pragma unroll
    for (int th = 0; th < 8; ++th)
#pragma unroll
        for (int ks = 0; ks < 4; ++ks)
            aw[th][ks] = *(const bf16x8*)(tw1s_u + (((th*4 + ks)*2 + hi)*32 + ln31)*8);
    bf16x8 w2f[4];     // epilogue A-frags, 16 VGPR
#pragma unroll
    for (int pk = 0; pk < 4; ++pk)
        w2f[pk] = *(const bf16x8*)(w2a_u + ((pk*2 + hi)*32 + ln31)*8);
    const bf16x8 tb1v = *(const bf16x8*)((const unsigned short*)(ws + WS_TB1V) + ln31*8);
    float fbi[32];
    {
        const float4* f4 = (const float4*)(ws + WS_FBQ);
#pragma unroll
        for (int i2 = 0; i2 < 8; ++i2) {
            float4 v = f4[hi*8 + i2];
            fbi[4*i2+0] = v.x; fbi[4*i2+1] = v.y;
            fbi[4*i2+2] = v.z; fbi[4*i2+3] = v.w;
        }
    }
    float c2r[8];
#pragma unroll
    for (int th = 0; th < 8; ++th) c2r[th] = ws[WS_C2 + th];
    u32x4 hbv = { hi ? 0u : 0x3F80u, 0u, 0u, 0u };   // const-1 B-frag, slot0
    const bf16x8 hbias = __builtin_bit_cast(bf16x8, hbv);

    // DMA: tile T (32 rows x 128 f32 = 16 KB) into wave-private buf b.
    // Source pre-swizzled (gchunk = ln31 ^ row), dest linear (rule #21; R12-validated).
    auto ISSUE = [&](int b, int T) {
#pragma unroll
        for (int it = 0; it < 16; ++it) {
            const int row = it*2 + hi;                 // 0..31
            const int gchunk = ln31 ^ row;
            const float* gp = x + (size_t)T * 4096 + row*128 + gchunk*4;
            __builtin_amdgcn_global_load_lds(
                (const __attribute__((address_space(1))) void*)gp,
                (__attribute__((address_space(3))) void*)(xls + (wave*2 + b)*1024 + it*64),
                16, 0, 0);
        }
    };

    ISSUE(0, t0);   // prologue

#pragma unroll 1
    for (int i = 0; i < NTW; ++i) {
        const int T = t0 + i;
        if (i + 1 < NTW) {
            ISSUE((i + 1) & 1, T + 1);
            asm volatile("s_waitcnt vmcnt(16)" ::: "memory");  // tile i landed; i+1 in flight
        } else {
            asm volatile("s_waitcnt vmcnt(0)" ::: "memory");
        }
        __builtin_amdgcn_sched_barrier(0);

        const char* xlb = (const char*)(xls + (wave*2 + (i & 1))*1024);
        const int tsel = t_arr[T*32 + ln31];

        // ---- GEMM1: h^T = fw @ x^T (+fb) ----
        f32x16 acc[2];
#pragma unroll
        for (int ht = 0; ht < 2; ++ht)
#pragma unroll
            for (int q = 0; q < 16; ++q) acc[ht][q] = fbi[ht*16 + q];
#pragma unroll
        for (int ks = 0; ks < 8; ++ks) {
            const int c0 = (ks*4 + hi*2)     ^ ln31;
            const int c1 = (ks*4 + hi*2 + 1) ^ ln31;
            float4 xa = *(const float4*)(xlb + ln31*512 + c0*16);
            float4 xb = *(const float4*)(xlb + ln31*512 + c1*16);
            bf16x8 xf;
            xf[0] = f2bf_fast(xa.x); xf[1] = f2bf_fast(xa.y);
            xf[2] = f2bf_fast(xa.z); xf[3] = f2bf_fast(xa.w);
            xf[4] = f2bf_fast(xb.x); xf[5] = f2bf_fast(xb.y);
            xf[6] = f2bf_fast(xb.z); xf[7] = f2bf_fast(xb.w);
            acc[0] = __builtin_amdgcn_mfma_f32_32x32x16_bf16(wa[ks][0], xf, acc[0], 0, 0, 0);
            acc[1] = __builtin_amdgcn_mfma_f32_32x32x16_bf16(wa[ks][1], xf, acc[1], 0, 0, 0);
        }

        // ---- relu -> chi-pack: lane-local GEMM2 B-frags ----
        bf16x8 hb[4];
        {
            unsigned w0[2][4], w1[2][4];
#pragma unroll
            for (int ht = 0; ht < 2; ++ht)
#pragma unroll
                for (int qq = 0; qq < 4; ++qq) {
                    float a0 = fmaxf(acc[ht][qq*4+0], 0.f);
                    float a1 = fmaxf(acc[ht][qq*4+1], 0.f);
                    float a2 = fmaxf(acc[ht][qq*4+2], 0.f);
                    float a3 = fmaxf(acc[ht][qq*4+3], 0.f);
                    w0[ht][qq] = pk_bf16(a0, a1);
                    w1[ht][qq] = pk_bf16(a2, a3);
                }
#pragma unroll
            for (int ks = 0; ks < 4; ++ks) {
                const int ht = ks >> 1, qa = (ks & 1) * 2;
                u32x4 wv = {w0[ht][qa], w1[ht][qa], w0[ht][qa+1], w1[ht][qa+1]};
                hb[ks] = __builtin_bit_cast(bf16x8, wv);
            }
        }

        // ---- GEMM2 dense 8 heads, bias-MFMA + chi2 MFMA epilogue ----
        float outv = 0.f;
#pragma unroll
        for (int th = 0; th < 8; ++th) {
            f32x16 z = {0.f};
            z = __builtin_amdgcn_mfma_f32_32x32x16_bf16(aw[th][0], hb[0], z, 0, 0, 0);
            z = __builtin_amdgcn_mfma_f32_32x32x16_bf16(aw[th][1], hb[1], z, 0, 0, 0);
            z = __builtin_amdgcn_mfma_f32_32x32x16_bf16(aw[th][2], hb[2], z, 0, 0, 0);
            z = __builtin_amdgcn_mfma_f32_32x32x16_bf16(aw[th][3], hb[3], z, 0, 0, 0);
            u32x4 tbv = { hi ? 0u : (unsigned)(unsigned short)tb1v[th], 0u, 0u, 0u };
            z = __builtin_amdgcn_mfma_f32_32x32x16_bf16(
                    __builtin_bit_cast(bf16x8, tbv), hbias, z, 0, 0, 0);

            bf16x8 zb[2];
#pragma unroll
            for (int kt = 0; kt < 2; ++kt) {
                u32x4 wv;
#pragma unroll
                for (int wd = 0; wd < 4; ++wd)
                    wv[wd] = pk_bf16(fmaxf(z[8*kt + 2*wd], 0.f),
                                     fmaxf(z[8*kt + 2*wd + 1], 0.f));
                zb[kt] = __builtin_bit_cast(bf16x8, wv);
            }
            f32x16 d = {0.f};
            d = __builtin_amdgcn_mfma_f32_32x32x16_bf16(w2f[0], zb[0], d, 0, 0, 0);
            d = __builtin_amdgcn_mfma_f32_32x32x16_bf16(w2f[1], zb[1], d, 0, 0, 0);
            d = __builtin_amdgcn_mfma_f32_32x32x16_bf16(w2f[2], zb[0], d, 0, 0, 0);
            d = __builtin_amdgcn_mfma_f32_32x32x16_bf16(w2f[3], zb[1], d, 0, 0, 0);

            float cand  = d[th & 3];
            float other = __shfl_xor(cand, 32);
            float val   = (hi == (th >> 2)) ? cand : other;
            outv = (th == tsel) ? val : outv;
        }
        outv += c2r[tsel];
        if (!hi) out[T*32 + ln31] = outv;
    }
}

extern "C" void kernel_launch(void* const* d_in, const int* in_sizes, int n_in,
                              void* d_out, int out_size, void* d_ws, size_t ws_size,
                              hipStream_t stream) {
    const float* x       = (const float*)d_in[0];
    const int*   t       = (const int*)  d_in[1];
    const float* fw      = (const float*)d_in[2];
    const float* fb      = (const float*)d_in[3];
    const float* f_gamma = (const float*)d_in[4];
    const float* f_beta  = (const float*)d_in[5];
    const float* f_mean  = (const float*)d_in[6];
    const float* f_var   = (const float*)d_in[7];
    const float* tw1     = (const float*)d_in[8];
    const float* tb1     = (const float*)d_in[9];
    const float* t_gamma = (const float*)d_in[10];
    const float* t_beta  = (const float*)d_in[11];
    const float* t_mean  = (const float*)d_in[12];
    const float* t_var   = (const float*)d_in[13];
    const float* tw2     = (const float*)d_in[14];
    const float* tb2     = (const float*)d_in[15];

    float* ws   = (float*)d_ws;
    float* outp = (float*)d_out;
    const int B = in_sizes[0] / 128;       // 262144
    const int tiles = B / 32;              // 8192

    tarnet_pre<<<2, 256, 0, stream>>>(fw, fb, f_gamma, f_beta, f_mean, f_var,
                                      tw1, tb1, t_gamma, t_beta, t_mean, t_var,
                                      tw2, tb2, ws);
    tarnet_main<<<tiles / (4 * NTW), 256, 0, stream>>>(x, t, ws, outp);
}

// Round 20
// 51.922 us; speedup vs baseline: 1.9892x; 1.2574x over previous
//
#include <hip/hip_runtime.h>
#include <hip/hip_bf16.h>
#include <cstdint>

#define EPS 1e-5f

typedef short bf16x8 __attribute__((ext_vector_type(8)));
typedef float f32x16 __attribute__((ext_vector_type(16)));
typedef unsigned int u32x4 __attribute__((ext_vector_type(4)));

// ws float-offsets
#define WS_TW1S 0        // 16384 ushort: chi-permuted GEMM2 A-frag layout
#define WS_FWQ  8192     // 8192 ushort: GEMM1 A-frag layout
#define WS_FBQ  12800    // 64 floats: [hi*32 + ht*16 + q]
#define WS_C2   12864    // 8 floats
#define WS_TB1V 12880    // 256 ushort: [r*8 + th] bf16 tb1s
#define WS_W2A  13056    // 2048 ushort: [((part*2+kt)*2+hi)*32+ln]*8 w2 A-frags

static __device__ __forceinline__ unsigned short f2bf(float f) {
    unsigned int u = __float_as_uint(f);
    u += 0x7fffu + ((u >> 16) & 1u);   // RNE
    return (unsigned short)(u >> 16);
}
static __device__ __forceinline__ short f2bf_fast(float f) {
    __hip_bfloat16 b = __float2bfloat16(f);
    return __builtin_bit_cast(short, b);
}
static __device__ __forceinline__ unsigned pk_bf16(float lo, float hi) {
    unsigned l = (unsigned)(unsigned short)__builtin_bit_cast(unsigned short, __float2bfloat16(lo));
    unsigned h = (unsigned)(unsigned short)__builtin_bit_cast(unsigned short, __float2bfloat16(hi));
    return l | (h << 16);
}

// chi  (GEMM1->GEMM2): j = ht*32+qq*8+4h+m -> ks = ht*2+(qq>>1), slot = 8h+(qq&1)*4+m
// chi2 (z->epilogue):  r = (e&3) + 8*((e>>2)&1) + 16*kt + 4*hi at slot 8*hi+e
__global__ void tarnet_pre(
    const float* __restrict__ fw, const float* __restrict__ fb,
    const float* __restrict__ f_gamma, const float* __restrict__ f_beta,
    const float* __restrict__ f_mean,  const float* __restrict__ f_var,
    const float* __restrict__ tw1, const float* __restrict__ tb1,
    const float* __restrict__ t_gamma, const float* __restrict__ t_beta,
    const float* __restrict__ t_mean,  const float* __restrict__ t_var,
    const float* __restrict__ tw2, const float* __restrict__ tb2,
    float* __restrict__ ws)
{
    __shared__ float fs[64], fsh[64];
    const int i = threadIdx.x;  // 256 threads
    if (i < 64) {
        float s = f_gamma[i] * rsqrtf(f_var[i] + EPS);
        fs[i]  = s;
        fsh[i] = f_beta[i] - f_mean[i] * s;
    }
    __syncthreads();

    unsigned short* tw1s_u = (unsigned short*)(ws + WS_TW1S);
    unsigned short* fwq_u  = (unsigned short*)(ws + WS_FWQ);
    unsigned short* tb1v_u = (unsigned short*)(ws + WS_TB1V);
    unsigned short* w2a_u  = (unsigned short*)(ws + WS_W2A);

    if (blockIdx.x == 0) {
        const int t = i >> 5, r = i & 31;
        const int idx = t * 32 + r;
        float tsc  = t_gamma[idx] * rsqrtf(t_var[idx] + EPS);
        float tb1s = tb1[idx];
        for (int j = 0; j < 64; ++j) {
            float w = tw1[idx * 64 + j];
            tb1s += w * fsh[j];
            int ht = j >> 5, qq = (j >> 3) & 3, h = (j >> 2) & 1, m = j & 3;
            int ks = ht * 2 + (qq >> 1);
            int ep = (qq & 1) * 4 + m;
            tw1s_u[(((t*4 + ks)*2 + h)*32 + r)*8 + ep] = f2bf(w * fs[j]);
        }
        tb1v_u[r*8 + t] = f2bf(tb1s);
        if (r == 0) {
            float a = tb2[t];
            for (int rr = 0; rr < 32; ++rr) {
                int id2 = t*32 + rr;
                float ts2 = t_gamma[id2] * rsqrtf(t_var[id2] + EPS);
                a += tw2[id2] * (t_beta[id2] - ts2 * t_mean[id2]);
            }
            ws[WS_C2 + t] = a;
        }
    } else {
        {   // fw conversion, frag-native
            const int hc = i >> 2, kq = (i & 3) * 32;
            for (int kk = 0; kk < 32; ++kk) {
                const int k = kq + kk;
                const int ks = k >> 4, h = (k >> 3) & 1, jj = k & 7;
                fwq_u[(((ks*2 + h)*64) + hc)*8 + jj] = f2bf(fw[hc*128 + k]);
            }
        }
        if (i < 64) {
            int ht = i >> 5, r32 = i & 31;
            int q  = ((r32 >> 3) << 2) | (r32 & 3);
            int hq = (r32 >> 2) & 1;
            ws[WS_FBQ + hq*32 + ht*16 + q] = fb[i];
        }
        {   // W2A: epilogue A-frags (R12-validated)
            const int ln = i & 31, hh = (i >> 5) & 1, kt = (i >> 6) & 1, part = i >> 7;
            const int base = (((part*2 + kt)*2 + hh)*32 + ln)*8;
            for (int e = 0; e < 8; ++e) {
                unsigned short v = 0;
                if (ln < 8) {
                    const int rr = (e & 3) + 8*((e >> 2) & 1) + 16*kt + 4*hh;
                    const int id2 = ln*32 + rr;
                    float tsc = t_gamma[id2] * rsqrtf(t_var[id2] + EPS);
                    float w = tw2[id2] * tsc;
                    if (part == 0) v = f2bf(w);
                    else {
                        float whi = __uint_as_float(((unsigned)f2bf(w)) << 16);
                        v = f2bf(w - whi);
                    }
                }
                w2a_u[base + e] = v;
            }
        }
    }
}

// 4 waves/block, 128-sample tile, 32 KB LDS (5 blocks/CU) -> 3 waves/SIMD target.
// GEMM2: MFMA bias + chi2 MFMA epilogue, head-pair interleaved for ILP.
__global__ __launch_bounds__(256, 3) void tarnet_main(
    const float* __restrict__ x, const int* __restrict__ t_arr,
    const float* __restrict__ ws, float* __restrict__ out)
{
    __shared__ unsigned short x_lds_u[128 * 128];   // 32 KB bf16, XOR-swizzled
    char* xl = (char*)x_lds_u;

    const int tid  = threadIdx.x;
    const int wave = tid >> 6, lane = tid & 63;
    const int ln31 = lane & 31, hi = lane >> 5;
    const int sbase = blockIdx.x * 128;

    {   // coalesced stage: 8 pair-iters x 32 B/lane contiguous (R8-validated)
        const float4* xg = (const float4*)(x + (size_t)sbase * 128);
#pragma unroll
        for (int it = 0; it < 8; ++it) {
            const int i = it * 256 + tid;
            float4 a = xg[2*i], b = xg[2*i + 1];
            bf16x8 v;
            v[0] = f2bf_fast(a.x); v[1] = f2bf_fast(a.y);
            v[2] = f2bf_fast(a.z); v[3] = f2bf_fast(a.w);
            v[4] = f2bf_fast(b.x); v[5] = f2bf_fast(b.y);
            v[6] = f2bf_fast(b.z); v[7] = f2bf_fast(b.w);
            const int row = i >> 4, pcol = i & 15;
            *(bf16x8*)(xl + row * 256 + ((pcol * 16) ^ ((row & 15) << 4))) = v;
        }
    }
    __syncthreads();

    const unsigned short* fwq_u  = (const unsigned short*)(ws + WS_FWQ);
    const unsigned short* tw1s_u = (const unsigned short*)(ws + WS_TW1S);
    const unsigned short* w2a_u  = (const unsigned short*)(ws + WS_W2A);

    // wave-invariant tables (small VGPR cost)
    bf16x8 w2f[4];
#pragma unroll
    for (int pk = 0; pk < 4; ++pk)
        w2f[pk] = *(const bf16x8*)(w2a_u + ((pk*2 + hi)*32 + ln31)*8);
    const bf16x8 tb1v = *(const bf16x8*)((const unsigned short*)(ws + WS_TB1V) + ln31*8);
    u32x4 hbv = { hi ? 0u : 0x3F80u, 0u, 0u, 0u };   // const-1 B-frag, slot0
    const bf16x8 hbias = __builtin_bit_cast(bf16x8, hbv);

    const int tsel = t_arr[sbase + wave * 32 + ln31];
    const int srow = wave * 32 + ln31;
    const int rb = srow * 256, swz = (srow & 15) << 4;

    // ---- GEMM1: h^T = fw @ x^T (+fb) ----
    f32x16 acc[2];
    {
        const float* fbq = ws + WS_FBQ;
#pragma unroll
        for (int ht = 0; ht < 2; ++ht)
#pragma unroll
            for (int q = 0; q < 16; ++q)
                acc[ht][q] = fbq[hi*32 + ht*16 + q];
    }
#pragma unroll
    for (int ks = 0; ks < 8; ++ks) {
        bf16x8 wa0 = *(const bf16x8*)(fwq_u + (((ks*2 + hi)*64) + ln31     )*8);
        bf16x8 wa1 = *(const bf16x8*)(fwq_u + (((ks*2 + hi)*64) + ln31 + 32)*8);
        bf16x8 xf  = *(const bf16x8*)(xl + rb + ((ks*32 + hi*16) ^ swz));
        acc[0] = __builtin_amdgcn_mfma_f32_32x32x16_bf16(wa0, xf, acc[0], 0, 0, 0);
        acc[1] = __builtin_amdgcn_mfma_f32_32x32x16_bf16(wa1, xf, acc[1], 0, 0, 0);
    }

    // ---- relu -> chi-pack: lane-local GEMM2 B-frags ----
    bf16x8 hb[4];
    {
        unsigned w0[2][4], w1[2][4];
#pragma unroll
        for (int ht = 0; ht < 2; ++ht)
#pragma unroll
            for (int qq = 0; qq < 4; ++qq) {
                float a0 = fmaxf(acc[ht][qq*4+0], 0.f);
                float a1 = fmaxf(acc[ht][qq*4+1], 0.f);
                float a2 = fmaxf(acc[ht][qq*4+2], 0.f);
                float a3 = fmaxf(acc[ht][qq*4+3], 0.f);
                w0[ht][qq] = pk_bf16(a0, a1);
                w1[ht][qq] = pk_bf16(a2, a3);
            }
#pragma unroll
        for (int ks = 0; ks < 4; ++ks) {
            const int ht = ks >> 1, qa = (ks & 1) * 2;
            u32x4 wv = {w0[ht][qa], w1[ht][qa], w0[ht][qa+1], w1[ht][qa+1]};
            hb[ks] = __builtin_bit_cast(bf16x8, wv);
        }
    }

    // ---- GEMM2 dense, head-PAIR interleaved (2 independent MFMA chains) ----
    float outv = 0.f;
#pragma unroll
    for (int tp = 0; tp < 4; ++tp) {
        const int ta = tp * 2, tb = tp * 2 + 1;
        f32x16 za = {0.f}, zc = {0.f};
#pragma unroll
        for (int ks = 0; ks < 4; ++ks) {
            bf16x8 awa = *(const bf16x8*)(tw1s_u + (((ta*4 + ks)*2 + hi)*32 + ln31)*8);
            bf16x8 awb = *(const bf16x8*)(tw1s_u + (((tb*4 + ks)*2 + hi)*32 + ln31)*8);
            za = __builtin_amdgcn_mfma_f32_32x32x16_bf16(awa, hb[ks], za, 0, 0, 0);
            zc = __builtin_amdgcn_mfma_f32_32x32x16_bf16(awb, hb[ks], zc, 0, 0, 0);
        }
        u32x4 tba = { hi ? 0u : (unsigned)(unsigned short)tb1v[ta], 0u, 0u, 0u };
        u32x4 tbb = { hi ? 0u : (unsigned)(unsigned short)tb1v[tb], 0u, 0u, 0u };
        za = __builtin_amdgcn_mfma_f32_32x32x16_bf16(
                 __builtin_bit_cast(bf16x8, tba), hbias, za, 0, 0, 0);
        zc = __builtin_amdgcn_mfma_f32_32x32x16_bf16(
                 __builtin_bit_cast(bf16x8, tbb), hbias, zc, 0, 0, 0);

        bf16x8 zba[2], zbb[2];
#pragma unroll
        for (int kt = 0; kt < 2; ++kt) {
            u32x4 wva, wvb;
#pragma unroll
            for (int wd = 0; wd < 4; ++wd) {
                wva[wd] = pk_bf16(fmaxf(za[8*kt + 2*wd], 0.f),
                                  fmaxf(za[8*kt + 2*wd + 1], 0.f));
                wvb[wd] = pk_bf16(fmaxf(zc[8*kt + 2*wd], 0.f),
                                  fmaxf(zc[8*kt + 2*wd + 1], 0.f));
            }
            zba[kt] = __builtin_bit_cast(bf16x8, wva);
            zbb[kt] = __builtin_bit_cast(bf16x8, wvb);
        }
        f32x16 da = {0.f}, db = {0.f};
        da = __builtin_amdgcn_mfma_f32_32x32x16_bf16(w2f[0], zba[0], da, 0, 0, 0);
        db = __builtin_amdgcn_mfma_f32_32x32x16_bf16(w2f[0], zbb[0], db, 0, 0, 0);
        da = __builtin_amdgcn_mfma_f32_32x32x16_bf16(w2f[1], zba[1], da, 0, 0, 0);
        db = __builtin_amdgcn_mfma_f32_32x32x16_bf16(w2f[1], zbb[1], db, 0, 0, 0);
        da = __builtin_amdgcn_mfma_f32_32x32x16_bf16(w2f[2], zba[0], da, 0, 0, 0);
        db = __builtin_amdgcn_mfma_f32_32x32x16_bf16(w2f[2], zbb[0], db, 0, 0, 0);
        da = __builtin_amdgcn_mfma_f32_32x32x16_bf16(w2f[3], zba[1], da, 0, 0, 0);
        db = __builtin_amdgcn_mfma_f32_32x32x16_bf16(w2f[3], zbb[1], db, 0, 0, 0);

        // row th lives at reg q=th&3, half hi=th>>2 (validated R12)
        {
            float cand  = da[ta & 3];
            float other = __shfl_xor(cand, 32);
            float val   = (hi == (ta >> 2)) ? cand : other;
            outv = (ta == tsel) ? val : outv;
        }
        {
            float cand  = db[tb & 3];
            float other = __shfl_xor(cand, 32);
            float val   = (hi == (tb >> 2)) ? cand : other;
            outv = (tb == tsel) ? val : outv;
        }
    }
    outv += ws[WS_C2 + tsel];
    if (!hi) out[sbase + wave * 32 + ln31] = outv;
}

extern "C" void kernel_launch(void* const* d_in, const int* in_sizes, int n_in,
                              void* d_out, int out_size, void* d_ws, size_t ws_size,
                              hipStream_t stream) {
    const float* x       = (const float*)d_in[0];
    const int*   t       = (const int*)  d_in[1];
    const float* fw      = (const float*)d_in[2];
    const float* fb      = (const float*)d_in[3];
    const float* f_gamma = (const float*)d_in[4];
    const float* f_beta  = (const float*)d_in[5];
    const float* f_mean  = (const float*)d_in[6];
    const float* f_var   = (const float*)d_in[7];
    const float* tw1     = (const float*)d_in[8];
    const float* tb1     = (const float*)d_in[9];
    const float* t_gamma = (const float*)d_in[10];
    const float* t_beta  = (const float*)d_in[11];
    const float* t_mean  = (const float*)d_in[12];
    const float* t_var   = (const float*)d_in[13];
    const float* tw2     = (const float*)d_in[14];
    const float* tb2     = (const float*)d_in[15];

    float* ws   = (float*)d_ws;
    float* outp = (float*)d_out;
    const int B = in_sizes[0] / 128;   // 262144

    tarnet_pre<<<2, 256, 0, stream>>>(fw, fb, f_gamma, f_beta, f_mean, f_var,
                                      tw1, tb1, t_gamma, t_beta, t_mean, t_var,
                                      tw2, tb2, ws);
    tarnet_main<<<B / 128, 256, 0, stream>>>(x, t, ws, outp);
}